// Round 6
// baseline (328.470 us; speedup 1.0000x reference)
//
#include <hip/hip_runtime.h>
#include <math.h>

#define Bsz 128
#define Usz 16
#define Dsz 256
#define Nsz 1024
#define Osz 256

typedef __attribute__((ext_vector_type(4))) float f32x4;
typedef __attribute__((ext_vector_type(8))) short bf16x8;
typedef __attribute__((ext_vector_type(4))) unsigned int u32x4;

union cell_u { u32x4 u; bf16x8 b; };

__device__ __forceinline__ unsigned int fbits(float f) {
    union { float f; unsigned int u; } v; v.f = f; return v.u;
}
// pack two f32 -> (bf16(hi)<<16)|bf16(lo) by truncation: 1 v_perm_b32
__device__ __forceinline__ unsigned int pk(float lo, float hi) {
    return __builtin_amdgcn_perm(fbits(hi), fbits(lo), 0x07060302u);
}
__device__ __forceinline__ bf16x8 pk8s(const float* x, float s) {
    float t[8];
    #pragma unroll
    for (int i = 0; i < 8; i++) t[i] = x[i] * s;
    cell_u r;
    r.u[0] = pk(t[0], t[1]); r.u[1] = pk(t[2], t[3]);
    r.u[2] = pk(t[4], t[5]); r.u[3] = pk(t[6], t[7]);
    return r.b;
}

// ---------------- lr = softmax_u(X·alr / T) ----------------
__global__ __launch_bounds__(256)
void lr_kernel(const float* __restrict__ X, const float* __restrict__ alr,
               const float* __restrict__ temp, float* __restrict__ lr)
{
    const int b = blockIdx.x;
    const int t = threadIdx.x;
    const int u = t >> 4;
    const int l = t & 15;
    const float* xp = X + ((size_t)b * Usz + u) * Dsz;
    const float* ap = alr + (size_t)u * Dsz;
    float s = 0.f;
    for (int d = l; d < Dsz; d += 16) s += xp[d] * ap[d];
    s += __shfl_down(s, 8, 16);
    s += __shfl_down(s, 4, 16);
    s += __shfl_down(s, 2, 16);
    s += __shfl_down(s, 1, 16);
    __shared__ float logits[16];
    if (l == 0) logits[u] = s;
    __syncthreads();
    if (t < 16) {
        const float T = temp[0];
        float m = -1e30f;
        #pragma unroll
        for (int i = 0; i < 16; i++) m = fmaxf(m, logits[i] / T);
        float sum = 0.f;
        #pragma unroll
        for (int i = 0; i < 16; i++) sum += expf(logits[i] / T - m);
        lr[(size_t)b * Usz + t] = expf(logits[t] / T - m) / sum;
    }
}

// ---- state: C = [X | state*sr] · [Win ; W] (K=1280), tanh/lr blend ----
// BARRIER-FREE: no LDS, each wave owns 32m x 32n, operands loaded straight
// into registers (A: k-contiguous dwordx4; B: coalesced 64B-per-16-lane
// scalar dwords), packed to bf16 via v_perm, 4 MFMA per K-step of 32.
// 1-step register double-buffer; compiler emits fine-grained vmcnt waits
// (no __syncthreads -> no vmcnt(0) drain).
// grid 512 = mt2 x nt16 x u16; block = 4 waves = 64m x 64n tile.
__global__ __launch_bounds__(256, 2)
void state_mfma(const float* __restrict__ X, const float* __restrict__ state,
                const float* __restrict__ W, const float* __restrict__ Win,
                const float* __restrict__ bias, const float* __restrict__ sr,
                const float* __restrict__ lr, float* __restrict__ out0)
{
    const int id = blockIdx.x;
    const int u  = id & 15;
    const int nt = (id >> 4) & 15;
    const int mt = id >> 8;                 // 0..1

    const int tid  = threadIdx.x;
    const int wave = tid >> 6, lane = tid & 63;
    const int l16  = lane & 15, kgl = lane >> 4;
    const int wm = wave & 1, wn = wave >> 1;

    const int row0 = mt * 64 + wm * 32 + l16;        // + 16*mi
    const int col0 = nt * 64 + wn * 32 + l16;        // + 16*ni

    const float sru = sr[u];

    const float* Ax0 = X + ((size_t)row0 * Usz + u) * Dsz;
    const float* Ax1 = X + ((size_t)(row0 + 16) * Usz + u) * Dsz;
    const float* Ae0 = state + ((size_t)row0 * Usz + u) * Nsz;
    const float* Ae1 = state + ((size_t)(row0 + 16) * Usz + u) * Nsz;
    const float* Bf  = Win + (size_t)u * Dsz * Nsz + col0;
    const float* Be  = W   + (size_t)u * Nsz * Nsz + col0;

    float a[2][2][8];   // [buf][mi][k8]
    float b[2][2][8];   // [buf][ni][k8]

    auto loadStep = [&](int step, int buf) {
        const int kb = step * 32 + kgl * 8;
        if (kb < Dsz) {
            *(f32x4*)&a[buf][0][0] = *(const f32x4*)(Ax0 + kb);
            *(f32x4*)&a[buf][0][4] = *(const f32x4*)(Ax0 + kb + 4);
            *(f32x4*)&a[buf][1][0] = *(const f32x4*)(Ax1 + kb);
            *(f32x4*)&a[buf][1][4] = *(const f32x4*)(Ax1 + kb + 4);
            const float* bp = Bf + (size_t)kb * Nsz;
            #pragma unroll
            for (int j = 0; j < 8; j++) {
                b[buf][0][j] = bp[(size_t)j * Nsz];
                b[buf][1][j] = bp[(size_t)j * Nsz + 16];
            }
        } else {
            const int kk = kb - Dsz;
            *(f32x4*)&a[buf][0][0] = *(const f32x4*)(Ae0 + kk);
            *(f32x4*)&a[buf][0][4] = *(const f32x4*)(Ae0 + kk + 4);
            *(f32x4*)&a[buf][1][0] = *(const f32x4*)(Ae1 + kk);
            *(f32x4*)&a[buf][1][4] = *(const f32x4*)(Ae1 + kk + 4);
            const float* bp = Be + (size_t)kk * Nsz;
            #pragma unroll
            for (int j = 0; j < 8; j++) {
                b[buf][0][j] = bp[(size_t)j * Nsz];
                b[buf][1][j] = bp[(size_t)j * Nsz + 16];
            }
        }
    };

    f32x4 acc[2][2] = {};
    loadStep(0, 0);

    for (int step = 0; step < 40; ++step) {
        const int cur = step & 1;
        if (step + 1 < 40) loadStep(step + 1, cur ^ 1);
        const float asc = (step < 8) ? 1.f : sru;    // fold sr into echo-A
        bf16x8 af[2], bf[2];
        af[0] = pk8s(a[cur][0], asc);
        af[1] = pk8s(a[cur][1], asc);
        bf[0] = pk8s(b[cur][0], 1.f);
        bf[1] = pk8s(b[cur][1], 1.f);
        #pragma unroll
        for (int mi = 0; mi < 2; mi++)
            #pragma unroll
            for (int ni = 0; ni < 2; ni++)
                acc[mi][ni] = __builtin_amdgcn_mfma_f32_16x16x32_bf16(af[mi], bf[ni], acc[mi][ni], 0, 0, 0);
    }

    // C/D layout: col=lane&15, row=(lane>>4)*4+reg (HW-verified R3-R5)
    #pragma unroll
    for (int ni = 0; ni < 2; ni++) {
        const int gcol = nt * 64 + wn * 32 + ni * 16 + l16;
        const float bi = bias[u * Nsz + gcol];
        #pragma unroll
        for (int mi = 0; mi < 2; mi++) {
            #pragma unroll
            for (int rg = 0; rg < 4; rg++) {
                const int grow = mt * 64 + wm * 32 + mi * 16 + kgl * 4 + rg;
                const size_t idx = ((size_t)grow * Usz + u) * Nsz + gcol;
                const float th = tanhf(acc[mi][ni][rg] + bi);
                const float sv = state[idx];
                const float lv = lr[grow * Usz + u];
                out0[idx] = (1.f - lv) * sv + lv * th;
            }
        }
    }
}

// ---- out1 = ns · Wout: barrier-free, wave = 16m x 16n, K=1024 (32 steps) ----
// grid 512 x 4 waves = 2048 waves = mt8 x ot16 x u16.
__global__ __launch_bounds__(256, 2)
void out_mfma(const float* __restrict__ ns, const float* __restrict__ Wout,
              float* __restrict__ out1)
{
    const int w  = blockIdx.x * 4 + (threadIdx.x >> 6);   // 0..2047
    const int u  = w & 15;
    const int ot = (w >> 4) & 15;
    const int mtw = w >> 8;                                // 0..7

    const int lane = threadIdx.x & 63;
    const int l16  = lane & 15, kgl = lane >> 4;

    const float* Ap = ns + ((size_t)(mtw * 16 + l16) * Usz + u) * Nsz;
    const float* Bp = Wout + (size_t)u * Nsz * Osz + ot * 16 + l16;

    float a[2][8], b[2][8];
    auto loadStep = [&](int step, int buf) {
        const int kb = step * 32 + kgl * 8;
        *(f32x4*)&a[buf][0] = *(const f32x4*)(Ap + kb);
        *(f32x4*)&a[buf][4] = *(const f32x4*)(Ap + kb + 4);
        const float* bp = Bp + (size_t)kb * Osz;
        #pragma unroll
        for (int j = 0; j < 8; j++) b[buf][j] = bp[(size_t)j * Osz];
    };

    f32x4 acc = {};
    loadStep(0, 0);
    for (int step = 0; step < 32; ++step) {
        const int cur = step & 1;
        if (step + 1 < 32) loadStep(step + 1, cur ^ 1);
        const bf16x8 af = pk8s(a[cur], 1.f);
        const bf16x8 bf = pk8s(b[cur], 1.f);
        acc = __builtin_amdgcn_mfma_f32_16x16x32_bf16(af, bf, acc, 0, 0, 0);
    }

    const int gcol = ot * 16 + l16;
    #pragma unroll
    for (int rg = 0; rg < 4; rg++) {
        const int grow = mtw * 16 + kgl * 4 + rg;
        out1[((size_t)grow * Usz + u) * Osz + gcol] = acc[rg];
    }
}

extern "C" void kernel_launch(void* const* d_in, const int* in_sizes, int n_in,
                              void* d_out, int out_size, void* d_ws, size_t ws_size,
                              hipStream_t stream)
{
    (void)in_sizes; (void)n_in; (void)out_size; (void)ws_size;
    const float* X     = (const float*)d_in[0];
    const float* state = (const float*)d_in[1];
    const float* W     = (const float*)d_in[2];
    const float* Win   = (const float*)d_in[3];
    const float* bias  = (const float*)d_in[4];
    const float* Wout  = (const float*)d_in[5];
    const float* sr    = (const float*)d_in[6];
    const float* alr   = (const float*)d_in[7];
    const float* temp  = (const float*)d_in[8];

    float* out0 = (float*)d_out;                      // (B,U,N)
    float* out1 = out0 + (size_t)Bsz * Usz * Nsz;     // (B,U,O)
    float* lr   = (float*)d_ws;                       // 8 KB

    lr_kernel<<<Bsz, 256, 0, stream>>>(X, alr, temp, lr);
    state_mfma<<<512, 256, 0, stream>>>(X, state, W, Win, bias, sr, lr, out0);
    out_mfma<<<512, 256, 0, stream>>>(out0, Wout, out1);
}

// Round 7
// 218.186 us; speedup vs baseline: 1.5055x; 1.5055x over previous
//
#include <hip/hip_runtime.h>
#include <math.h>

#define Bsz 128
#define Usz 16
#define Dsz 256
#define Nsz 1024
#define Osz 256

typedef __attribute__((ext_vector_type(4))) float f32x4;
typedef __attribute__((ext_vector_type(8))) short bf16x8;
typedef __attribute__((ext_vector_type(4))) unsigned int u32x4;

union cell_u { u32x4 u; bf16x8 b; };

__device__ __forceinline__ unsigned int fbits(float f) {
    union { float f; unsigned int u; } v; v.f = f; return v.u;
}
// pack two f32 -> (bf16(hi)<<16)|bf16(lo) by truncation: 1 v_perm_b32
__device__ __forceinline__ unsigned int pk(float lo, float hi) {
    return __builtin_amdgcn_perm(fbits(hi), fbits(lo), 0x07060302u);
}
__device__ __forceinline__ bf16x8 pk8s(const float* x, float s) {
    float t[8];
    #pragma unroll
    for (int i = 0; i < 8; i++) t[i] = x[i] * s;
    cell_u r;
    r.u[0] = pk(t[0], t[1]); r.u[1] = pk(t[2], t[3]);
    r.u[2] = pk(t[4], t[5]); r.u[3] = pk(t[6], t[7]);
    return r.b;
}

// ---------------- lr = softmax_u(X·alr / T) ----------------
__global__ __launch_bounds__(256)
void lr_kernel(const float* __restrict__ X, const float* __restrict__ alr,
               const float* __restrict__ temp, float* __restrict__ lr)
{
    const int b = blockIdx.x;
    const int t = threadIdx.x;
    const int u = t >> 4;
    const int l = t & 15;
    const float* xp = X + ((size_t)b * Usz + u) * Dsz;
    const float* ap = alr + (size_t)u * Dsz;
    float s = 0.f;
    for (int d = l; d < Dsz; d += 16) s += xp[d] * ap[d];
    s += __shfl_down(s, 8, 16);
    s += __shfl_down(s, 4, 16);
    s += __shfl_down(s, 2, 16);
    s += __shfl_down(s, 1, 16);
    __shared__ float logits[16];
    if (l == 0) logits[u] = s;
    __syncthreads();
    if (t < 16) {
        const float T = temp[0];
        float m = -1e30f;
        #pragma unroll
        for (int i = 0; i < 16; i++) m = fmaxf(m, logits[i] / T);
        float sum = 0.f;
        #pragma unroll
        for (int i = 0; i < 16; i++) sum += expf(logits[i] / T - m);
        lr[(size_t)b * Usz + t] = expf(logits[t] / T - m) / sum;
    }
}

// ---- state: C = [X | state*sr] · [Win ; W] (K=1280), tanh/lr blend ----
// BARRIER-FREE, register-resident. Double buffer uses STATICALLY-NAMED
// arrays (manual 2-step unroll) so SROA keeps them in VGPRs — R6's runtime
// buf-index demoted them to scratch (VGPR_Count=64 was the tell).
// wave = 32m x 32n, block = 64m x 64n, grid 512 = mt2 x nt16 x u16.
__global__ __launch_bounds__(256)
void state_mfma(const float* __restrict__ X, const float* __restrict__ state,
                const float* __restrict__ W, const float* __restrict__ Win,
                const float* __restrict__ bias, const float* __restrict__ sr,
                const float* __restrict__ lr, float* __restrict__ out0)
{
    const int id = blockIdx.x;
    const int u  = id & 15;
    const int nt = (id >> 4) & 15;
    const int mt = id >> 8;                 // 0..1 (id, id+256 -> same XCD)

    const int tid  = threadIdx.x;
    const int wave = tid >> 6, lane = tid & 63;
    const int l16  = lane & 15, kgl = lane >> 4;
    const int wm = wave & 1, wn = wave >> 1;

    const int row0 = mt * 64 + wm * 32 + l16;
    const int col0 = nt * 64 + wn * 32 + l16;

    const float sru = sr[u];

    const float* Ax0 = X + ((size_t)row0 * Usz + u) * Dsz;
    const float* Ax1 = X + ((size_t)(row0 + 16) * Usz + u) * Dsz;
    const float* Ae0 = state + ((size_t)row0 * Usz + u) * Nsz;
    const float* Ae1 = state + ((size_t)(row0 + 16) * Usz + u) * Nsz;
    const float* Bf  = Win + (size_t)u * Dsz * Nsz + col0;
    const float* Be  = W   + (size_t)u * Nsz * Nsz + col0;

    f32x4 acc[2][2] = {};

    auto loadStep = [&](int step, float (&A0)[8], float (&A1)[8],
                        float (&B0)[8], float (&B1)[8]) {
        const int kb = step * 32 + kgl * 8;
        const float *pa0, *pa1, *pb;
        if (kb < Dsz) {
            pa0 = Ax0 + kb; pa1 = Ax1 + kb; pb = Bf + (size_t)kb * Nsz;
        } else {
            const int kk = kb - Dsz;
            pa0 = Ae0 + kk; pa1 = Ae1 + kk; pb = Be + (size_t)kk * Nsz;
        }
        *(f32x4*)&A0[0] = *(const f32x4*)pa0;
        *(f32x4*)&A0[4] = *(const f32x4*)(pa0 + 4);
        *(f32x4*)&A1[0] = *(const f32x4*)pa1;
        *(f32x4*)&A1[4] = *(const f32x4*)(pa1 + 4);
        #pragma unroll
        for (int j = 0; j < 8; j++) {
            B0[j] = pb[(size_t)j * Nsz];
            B1[j] = pb[(size_t)j * Nsz + 16];
        }
    };
    auto compute = [&](int step, float (&A0)[8], float (&A1)[8],
                       float (&B0)[8], float (&B1)[8]) {
        const float asc = (step < 8) ? 1.f : sru;   // fold sr into echo-A
        const bf16x8 af0 = pk8s(A0, asc), af1 = pk8s(A1, asc);
        const bf16x8 bf0 = pk8s(B0, 1.f), bf1 = pk8s(B1, 1.f);
        acc[0][0] = __builtin_amdgcn_mfma_f32_16x16x32_bf16(af0, bf0, acc[0][0], 0, 0, 0);
        acc[0][1] = __builtin_amdgcn_mfma_f32_16x16x32_bf16(af0, bf1, acc[0][1], 0, 0, 0);
        acc[1][0] = __builtin_amdgcn_mfma_f32_16x16x32_bf16(af1, bf0, acc[1][0], 0, 0, 0);
        acc[1][1] = __builtin_amdgcn_mfma_f32_16x16x32_bf16(af1, bf1, acc[1][1], 0, 0, 0);
    };

    float A0a[8], A1a[8], B0a[8], B1a[8];
    float A0b[8], A1b[8], B0b[8], B1b[8];

    loadStep(0, A0a, A1a, B0a, B1a);
    for (int s = 0; s < 40; s += 2) {
        loadStep(s + 1, A0b, A1b, B0b, B1b);   // s+1 <= 39 always
        compute(s, A0a, A1a, B0a, B1a);
        if (s + 2 < 40) loadStep(s + 2, A0a, A1a, B0a, B1a);
        compute(s + 1, A0b, A1b, B0b, B1b);
    }

    // C/D layout: col=lane&15, row=(lane>>4)*4+reg (HW-verified R3-R6)
    #pragma unroll
    for (int ni = 0; ni < 2; ni++) {
        const int gcol = nt * 64 + wn * 32 + ni * 16 + l16;
        const float bi = bias[u * Nsz + gcol];
        #pragma unroll
        for (int mi = 0; mi < 2; mi++) {
            #pragma unroll
            for (int rg = 0; rg < 4; rg++) {
                const int grow = mt * 64 + wm * 32 + mi * 16 + kgl * 4 + rg;
                const size_t idx = ((size_t)grow * Usz + u) * Nsz + gcol;
                const float th = tanhf(acc[mi][ni][rg] + bi);
                const float sv = state[idx];
                const float lv = lr[grow * Usz + u];
                out0[idx] = (1.f - lv) * sv + lv * th;
            }
        }
    }
}

// ---- out1 = ns · Wout: barrier-free, wave = 16m x 16n, 32 K-steps ----
// grid 512 x 4 waves = 2048 waves = mt8 x ot16 x u16. Static dbuf arrays.
__global__ __launch_bounds__(256)
void out_mfma(const float* __restrict__ ns, const float* __restrict__ Wout,
              float* __restrict__ out1)
{
    const int w  = blockIdx.x * 4 + (threadIdx.x >> 6);   // 0..2047
    const int u  = w & 15;
    const int ot = (w >> 4) & 15;
    const int mtw = w >> 8;                                // 0..7

    const int lane = threadIdx.x & 63;
    const int l16  = lane & 15, kgl = lane >> 4;

    const float* Ap = ns + ((size_t)(mtw * 16 + l16) * Usz + u) * Nsz;
    const float* Bp = Wout + (size_t)u * Nsz * Osz + ot * 16 + l16;

    f32x4 acc = {};

    auto loadStep = [&](int step, float (&A)[8], float (&B)[8]) {
        const int kb = step * 32 + kgl * 8;
        *(f32x4*)&A[0] = *(const f32x4*)(Ap + kb);
        *(f32x4*)&A[4] = *(const f32x4*)(Ap + kb + 4);
        const float* bp = Bp + (size_t)kb * Osz;
        #pragma unroll
        for (int j = 0; j < 8; j++) B[j] = bp[(size_t)j * Osz];
    };
    auto compute = [&](float (&A)[8], float (&B)[8]) {
        const bf16x8 af = pk8s(A, 1.f);
        const bf16x8 bf = pk8s(B, 1.f);
        acc = __builtin_amdgcn_mfma_f32_16x16x32_bf16(af, bf, acc, 0, 0, 0);
    };

    float Aa[8], Ba[8], Ab[8], Bb[8];
    loadStep(0, Aa, Ba);
    for (int s = 0; s < 32; s += 2) {
        loadStep(s + 1, Ab, Bb);
        compute(Aa, Ba);
        if (s + 2 < 32) loadStep(s + 2, Aa, Ba);
        compute(Ab, Bb);
    }

    const int gcol = ot * 16 + l16;
    #pragma unroll
    for (int rg = 0; rg < 4; rg++) {
        const int grow = mtw * 16 + kgl * 4 + rg;
        out1[((size_t)grow * Usz + u) * Osz + gcol] = acc[rg];
    }
}

extern "C" void kernel_launch(void* const* d_in, const int* in_sizes, int n_in,
                              void* d_out, int out_size, void* d_ws, size_t ws_size,
                              hipStream_t stream)
{
    (void)in_sizes; (void)n_in; (void)out_size; (void)ws_size;
    const float* X     = (const float*)d_in[0];
    const float* state = (const float*)d_in[1];
    const float* W     = (const float*)d_in[2];
    const float* Win   = (const float*)d_in[3];
    const float* bias  = (const float*)d_in[4];
    const float* Wout  = (const float*)d_in[5];
    const float* sr    = (const float*)d_in[6];
    const float* alr   = (const float*)d_in[7];
    const float* temp  = (const float*)d_in[8];

    float* out0 = (float*)d_out;                      // (B,U,N)
    float* out1 = out0 + (size_t)Bsz * Usz * Nsz;     // (B,U,O)
    float* lr   = (float*)d_ws;                       // 8 KB

    lr_kernel<<<Bsz, 256, 0, stream>>>(X, alr, temp, lr);
    state_mfma<<<512, 256, 0, stream>>>(X, state, W, Win, bias, sr, lr, out0);
    out_mfma<<<512, 256, 0, stream>>>(out0, Wout, out1);
}

// Round 8
// 216.664 us; speedup vs baseline: 1.5160x; 1.0070x over previous
//
#include <hip/hip_runtime.h>
#include <math.h>

#define Bsz 128
#define Usz 16
#define Dsz 256
#define Nsz 1024
#define Osz 256

typedef __attribute__((ext_vector_type(4))) float f32x4;
typedef __attribute__((ext_vector_type(8))) short bf16x8;
typedef __attribute__((ext_vector_type(4))) unsigned int u32x4;

union cell_u { u32x4 u; bf16x8 b; };

struct F8 { f32x4 lo, hi; };          // 8 floats, pure SSA (no arrays!)

__device__ __forceinline__ unsigned int fbits(float f) {
    union { float f; unsigned int u; } v; v.f = f; return v.u;
}
// pack two f32 -> (bf16(hi)<<16)|bf16(lo) by truncation: 1 v_perm_b32
__device__ __forceinline__ unsigned int pk(float lo, float hi) {
    return __builtin_amdgcn_perm(fbits(hi), fbits(lo), 0x07060302u);
}
__device__ __forceinline__ bf16x8 pkF8(F8 f, float s) {
    f.lo *= s; f.hi *= s;
    cell_u r;
    r.u[0] = pk(f.lo[0], f.lo[1]); r.u[1] = pk(f.lo[2], f.lo[3]);
    r.u[2] = pk(f.hi[0], f.hi[1]); r.u[3] = pk(f.hi[2], f.hi[3]);
    return r.b;
}
__device__ __forceinline__ F8 ld8c(const float* p) {        // contiguous
    F8 r; r.lo = *(const f32x4*)p; r.hi = *(const f32x4*)(p + 4); return r;
}
__device__ __forceinline__ F8 ld8s(const float* p, int str) { // strided
    F8 r;
    r.lo[0] = p[0];              r.lo[1] = p[(size_t)str];
    r.lo[2] = p[2 * (size_t)str]; r.lo[3] = p[3 * (size_t)str];
    r.hi[0] = p[4 * (size_t)str]; r.hi[1] = p[5 * (size_t)str];
    r.hi[2] = p[6 * (size_t)str]; r.hi[3] = p[7 * (size_t)str];
    return r;
}

// ---------------- lr = softmax_u(X·alr / T) ----------------
__global__ __launch_bounds__(256)
void lr_kernel(const float* __restrict__ X, const float* __restrict__ alr,
               const float* __restrict__ temp, float* __restrict__ lr)
{
    const int b = blockIdx.x;
    const int t = threadIdx.x;
    const int u = t >> 4;
    const int l = t & 15;
    const float* xp = X + ((size_t)b * Usz + u) * Dsz;
    const float* ap = alr + (size_t)u * Dsz;
    float s = 0.f;
    for (int d = l; d < Dsz; d += 16) s += xp[d] * ap[d];
    s += __shfl_down(s, 8, 16);
    s += __shfl_down(s, 4, 16);
    s += __shfl_down(s, 2, 16);
    s += __shfl_down(s, 1, 16);
    __shared__ float logits[16];
    if (l == 0) logits[u] = s;
    __syncthreads();
    if (t < 16) {
        const float T = temp[0];
        float m = -1e30f;
        #pragma unroll
        for (int i = 0; i < 16; i++) m = fmaxf(m, logits[i] / T);
        float sum = 0.f;
        #pragma unroll
        for (int i = 0; i < 16; i++) sum += expf(logits[i] / T - m);
        lr[(size_t)b * Usz + t] = expf(logits[t] / T - m) / sum;
    }
}

// ---- state: C = [X | state*sr] · [Win ; W] (K=1280), tanh/lr blend ----
// BARRIER-FREE + pure-SSA register pipeline. All per-step operands live in
// by-value F8/Step structs of f32x4 (no local arrays, no references, no
// address-taken) so SROA keeps them in VGPRs. R6/R7 failed because their
// float[8] buffers were demoted to scratch (VGPR_Count stuck at 64).
// wave = 32m x 32n, block 64m x 64n, grid 512 = mt2 x nt16 x u16.
struct Step { F8 a0, a1, b0, b1; };

__global__ __launch_bounds__(256)
void state_mfma(const float* __restrict__ X, const float* __restrict__ state,
                const float* __restrict__ W, const float* __restrict__ Win,
                const float* __restrict__ bias, const float* __restrict__ sr,
                const float* __restrict__ lr, float* __restrict__ out0)
{
    const int id = blockIdx.x;
    const int u  = id & 15;
    const int nt = (id >> 4) & 15;
    const int mt = id >> 8;                 // 0..1

    const int tid  = threadIdx.x;
    const int wave = tid >> 6, lane = tid & 63;
    const int l16  = lane & 15, kgl = lane >> 4;
    const int wm = wave & 1, wn = wave >> 1;

    const int row0 = mt * 64 + wm * 32 + l16;
    const int col0 = nt * 64 + wn * 32 + l16;

    const float sru = sr[u];

    const float* Ax0 = X + ((size_t)row0 * Usz + u) * Dsz;
    const float* Ax1 = X + ((size_t)(row0 + 16) * Usz + u) * Dsz;
    const float* Ae0 = state + ((size_t)row0 * Usz + u) * Nsz;
    const float* Ae1 = state + ((size_t)(row0 + 16) * Usz + u) * Nsz;
    const float* Bf  = Win + (size_t)u * Dsz * Nsz + col0;
    const float* Be  = W   + (size_t)u * Nsz * Nsz + col0;

    f32x4 acc[2][2] = {};   // constant-indexed only

    auto ldS = [&](int s) -> Step {
        const int kb = s * 32 + kgl * 8;
        Step st;
        if (kb < Dsz) {
            st.a0 = ld8c(Ax0 + kb);
            st.a1 = ld8c(Ax1 + kb);
            const float* pb = Bf + (size_t)kb * Nsz;
            st.b0 = ld8s(pb, Nsz);
            st.b1 = ld8s(pb + 16, Nsz);
        } else {
            const int kk = kb - Dsz;
            st.a0 = ld8c(Ae0 + kk);
            st.a1 = ld8c(Ae1 + kk);
            const float* pb = Be + (size_t)kk * Nsz;
            st.b0 = ld8s(pb, Nsz);
            st.b1 = ld8s(pb + 16, Nsz);
        }
        return st;
    };
    auto compute = [&](Step st, int s) {
        const float asc = (s < 8) ? 1.f : sru;   // fold sr into echo-A
        const bf16x8 af0 = pkF8(st.a0, asc), af1 = pkF8(st.a1, asc);
        const bf16x8 bf0 = pkF8(st.b0, 1.f), bf1 = pkF8(st.b1, 1.f);
        acc[0][0] = __builtin_amdgcn_mfma_f32_16x16x32_bf16(af0, bf0, acc[0][0], 0, 0, 0);
        acc[0][1] = __builtin_amdgcn_mfma_f32_16x16x32_bf16(af0, bf1, acc[0][1], 0, 0, 0);
        acc[1][0] = __builtin_amdgcn_mfma_f32_16x16x32_bf16(af1, bf0, acc[1][0], 0, 0, 0);
        acc[1][1] = __builtin_amdgcn_mfma_f32_16x16x32_bf16(af1, bf1, acc[1][1], 0, 0, 0);
    };

    Step sa = ldS(0);
    for (int s = 0; s < 40; s += 2) {
        Step sb = ldS(s + 1);              // s+1 <= 39
        compute(sa, s);
        if (s + 2 < 40) sa = ldS(s + 2);
        compute(sb, s + 1);
    }

    // C/D layout: col=lane&15, row=(lane>>4)*4+reg (HW-verified R3-R7)
    #pragma unroll
    for (int ni = 0; ni < 2; ni++) {
        const int gcol = nt * 64 + wn * 32 + ni * 16 + l16;
        const float bi = bias[u * Nsz + gcol];
        #pragma unroll
        for (int mi = 0; mi < 2; mi++) {
            #pragma unroll
            for (int rg = 0; rg < 4; rg++) {
                const int grow = mt * 64 + wm * 32 + mi * 16 + kgl * 4 + rg;
                const size_t idx = ((size_t)grow * Usz + u) * Nsz + gcol;
                const float th = tanhf(acc[mi][ni][rg] + bi);
                const float sv = state[idx];
                const float lv = lr[grow * Usz + u];
                out0[idx] = (1.f - lv) * sv + lv * th;
            }
        }
    }
}

// ---- out1 = ns · Wout: barrier-free SSA, wave = 16m x 16n, 32 K-steps ----
// grid 512 x 4 waves = 2048 waves = mt8 x ot16 x u16.
__global__ __launch_bounds__(256)
void out_mfma(const float* __restrict__ ns, const float* __restrict__ Wout,
              float* __restrict__ out1)
{
    const int w  = blockIdx.x * 4 + (threadIdx.x >> 6);   // 0..2047
    const int u  = w & 15;
    const int ot = (w >> 4) & 15;
    const int mtw = w >> 8;                                // 0..7

    const int lane = threadIdx.x & 63;
    const int l16  = lane & 15, kgl = lane >> 4;

    const float* Ap = ns + ((size_t)(mtw * 16 + l16) * Usz + u) * Nsz;
    const float* Bp = Wout + (size_t)u * Nsz * Osz + ot * 16 + l16;

    f32x4 acc = {};

    struct Step2 { F8 a, b; };
    auto ldS = [&](int s) -> Step2 {
        const int kb = s * 32 + kgl * 8;
        Step2 st;
        st.a = ld8c(Ap + kb);
        st.b = ld8s(Bp + (size_t)kb * Osz, Osz);
        return st;
    };
    auto compute = [&](Step2 st) {
        const bf16x8 af = pkF8(st.a, 1.f);
        const bf16x8 bf = pkF8(st.b, 1.f);
        acc = __builtin_amdgcn_mfma_f32_16x16x32_bf16(af, bf, acc, 0, 0, 0);
    };

    Step2 sa = ldS(0);
    for (int s = 0; s < 32; s += 2) {
        Step2 sb = ldS(s + 1);
        compute(sa);
        if (s + 2 < 32) sa = ldS(s + 2);
        compute(sb);
    }

    const int gcol = ot * 16 + l16;
    #pragma unroll
    for (int rg = 0; rg < 4; rg++) {
        const int grow = mtw * 16 + kgl * 4 + rg;
        out1[((size_t)grow * Usz + u) * Osz + gcol] = acc[rg];
    }
}

extern "C" void kernel_launch(void* const* d_in, const int* in_sizes, int n_in,
                              void* d_out, int out_size, void* d_ws, size_t ws_size,
                              hipStream_t stream)
{
    (void)in_sizes; (void)n_in; (void)out_size; (void)ws_size;
    const float* X     = (const float*)d_in[0];
    const float* state = (const float*)d_in[1];
    const float* W     = (const float*)d_in[2];
    const float* Win   = (const float*)d_in[3];
    const float* bias  = (const float*)d_in[4];
    const float* Wout  = (const float*)d_in[5];
    const float* sr    = (const float*)d_in[6];
    const float* alr   = (const float*)d_in[7];
    const float* temp  = (const float*)d_in[8];

    float* out0 = (float*)d_out;                      // (B,U,N)
    float* out1 = out0 + (size_t)Bsz * Usz * Nsz;     // (B,U,O)
    float* lr   = (float*)d_ws;                       // 8 KB

    lr_kernel<<<Bsz, 256, 0, stream>>>(X, alr, temp, lr);
    state_mfma<<<512, 256, 0, stream>>>(X, state, W, Win, bias, sr, lr, out0);
    out_mfma<<<512, 256, 0, stream>>>(out0, Wout, out1);
}